// Round 1
// baseline (472.293 us; speedup 1.0000x reference)
//
#include <hip/hip_runtime.h>
#include <math.h>

#define BB 4096
#define TT 200
#define HH 64
#define NTB (BB*TT)

// ---------------- prep: WE = Wa + Wc (effective he-weight) ----------------
__global__ __launch_bounds__(256) void k_prep_we(const float* __restrict__ auW1,
                                                 float* __restrict__ WE) {
  int i = blockIdx.x * 256 + threadIdx.x;
  if (i < 64 * 36) WE[i] = auW1[i] + auW1[128 * 36 + i];
}

// ---------------- prep: tb[b][36] = ie_b @ (Wb - Wc) + au_b1 ----------------
__global__ __launch_bounds__(64) void k_prep_tb(const int* __restrict__ item,
                                                const float* __restrict__ Itab,
                                                const float* __restrict__ auW1,
                                                const float* __restrict__ auB1,
                                                float* __restrict__ TBuf) {
  int b = blockIdx.x, tid = threadIdx.x;
  __shared__ float sIe[64];
  int it = item[b];
  sIe[tid] = Itab[(size_t)it * 64 + tid];
  __syncthreads();
  if (tid < 36) {
    float a = auB1[tid];
    for (int k = 0; k < 64; ++k)
      a += sIe[k] * (auW1[(64 + k) * 36 + tid] - auW1[(128 + k) * 36 + tid]);
    TBuf[b * 36 + tid] = a;
  }
}

// ---------------- pass 1: pre-activations -> per-block stats partials ----------------
__global__ __launch_bounds__(256) void k_au1(const int* __restrict__ hist,
                                             const int* __restrict__ item,
                                             const float* __restrict__ Itab,
                                             const float* __restrict__ WE,
                                             const float* __restrict__ TBuf,
                                             const float* __restrict__ auW1,
                                             float* __restrict__ PART) {
  int b = blockIdx.x, tid = threadIdx.x;
  __shared__ float sHe[TT * 65];
  __shared__ float sIe[64];
  __shared__ int sRows[TT];
  if (tid < TT) sRows[tid] = hist[b * TT + tid];
  if (tid >= 192) sIe[tid - 192] = Itab[(size_t)item[b] * 64 + (tid - 192)];
  __syncthreads();
  for (int idx = tid; idx < TT * 64; idx += 256) {
    int r = idx >> 6, k = idx & 63;
    sHe[r * 65 + k] = Itab[(size_t)sRows[r] * 64 + k];
  }
  __syncthreads();
  int t = tid;
  float acc[36];
  if (t < TT) {
    const float* tb = TBuf + b * 36;
#pragma unroll
    for (int j = 0; j < 36; ++j) acc[j] = tb[j];
    const float* WD = auW1 + 192 * 36;
    for (int k = 0; k < 64; ++k) {
      float hk = sHe[t * 65 + k];
      float gk = hk * sIe[k];
      const float4* we4 = (const float4*)(WE + k * 36);
      const float4* wd4 = (const float4*)(WD + k * 36);
#pragma unroll
      for (int jg = 0; jg < 9; ++jg) {
        float4 e = we4[jg], d = wd4[jg];
        acc[jg * 4 + 0] += hk * e.x + gk * d.x;
        acc[jg * 4 + 1] += hk * e.y + gk * d.y;
        acc[jg * 4 + 2] += hk * e.z + gk * d.z;
        acc[jg * 4 + 3] += hk * e.w + gk * d.w;
      }
    }
  }
  __syncthreads();            // sHe dead -> reuse as pre-store
  float* sPre = sHe;          // stride 37
  if (t < TT) {
#pragma unroll
    for (int j = 0; j < 36; ++j) sPre[t * 37 + j] = acc[j];
  }
  __syncthreads();
  if (tid < 36) {
    float s1 = 0.f, s2 = 0.f;
    for (int r = 0; r < TT; ++r) {
      float v = sPre[r * 37 + tid];
      s1 += v;
      s2 += v * v;
    }
    PART[b * 72 + tid] = s1;
    PART[b * 72 + 36 + tid] = s2;
  }
}

// ---------------- AU stats finalize (deterministic fixed-order) ----------------
__global__ __launch_bounds__(256) void k_aust(const float* __restrict__ PART,
                                              float* __restrict__ AUST) {
  int ch = blockIdx.x, tid = threadIdx.x;
  float s1 = 0.f, s2 = 0.f;
  for (int bb = tid; bb < BB; bb += 256) {
    s1 += PART[bb * 72 + ch];
    s2 += PART[bb * 72 + 36 + ch];
  }
  __shared__ float r1[256], r2[256];
  r1[tid] = s1;
  r2[tid] = s2;
  __syncthreads();
  for (int off = 128; off > 0; off >>= 1) {
    if (tid < off) { r1[tid] += r1[tid + off]; r2[tid] += r2[tid + off]; }
    __syncthreads();
  }
  if (tid == 0) {
    float m = r1[0] / (float)NTB;
    float var = r2[0] / (float)NTB - m * m;
    AUST[ch] = m;
    AUST[36 + ch] = 1.0f / sqrtf(var + 1e-8f);
  }
}

// ---------------- pass 2: recompute pre, dice, weights, pool cur, fused MLP layer1 pre ----------------
__global__ __launch_bounds__(256) void k_au2(
    const int* __restrict__ hist, const int* __restrict__ item,
    const int* __restrict__ user, const int* __restrict__ cate,
    const float* __restrict__ Itab, const float* __restrict__ Utab,
    const float* __restrict__ Ctab, const float* __restrict__ WE,
    const float* __restrict__ TBuf, const float* __restrict__ auW1,
    const float* __restrict__ AUST, const float* __restrict__ auA1,
    const float* __restrict__ auW2, const float* __restrict__ auB2,
    const float* __restrict__ W1, const float* __restrict__ b1,
    float* __restrict__ Y1) {
  int b = blockIdx.x, tid = threadIdx.x;
  __shared__ float sHe[TT * 65];
  __shared__ float sIe[64];
  __shared__ int sRows[TT];
  __shared__ float sW[TT];
  __shared__ float sPart[256];
  __shared__ float sX[256];
  if (tid < TT) sRows[tid] = hist[b * TT + tid];
  if (tid >= 192) sIe[tid - 192] = Itab[(size_t)item[b] * 64 + (tid - 192)];
  __syncthreads();
  for (int idx = tid; idx < TT * 64; idx += 256) {
    int r = idx >> 6, k = idx & 63;
    sHe[r * 65 + k] = Itab[(size_t)sRows[r] * 64 + k];
  }
  __syncthreads();
  int t = tid;
  if (t < TT) {
    float acc[36];
    const float* tb = TBuf + b * 36;
#pragma unroll
    for (int j = 0; j < 36; ++j) acc[j] = tb[j];
    const float* WD = auW1 + 192 * 36;
    for (int k = 0; k < 64; ++k) {
      float hk = sHe[t * 65 + k];
      float gk = hk * sIe[k];
      const float4* we4 = (const float4*)(WE + k * 36);
      const float4* wd4 = (const float4*)(WD + k * 36);
#pragma unroll
      for (int jg = 0; jg < 9; ++jg) {
        float4 e = we4[jg], d = wd4[jg];
        acc[jg * 4 + 0] += hk * e.x + gk * d.x;
        acc[jg * 4 + 1] += hk * e.y + gk * d.y;
        acc[jg * 4 + 2] += hk * e.z + gk * d.z;
        acc[jg * 4 + 3] += hk * e.w + gk * d.w;
      }
    }
    float w = auB2[0];
#pragma unroll
    for (int j = 0; j < 36; ++j) {
      float x = acc[j];
      float xh = (x - AUST[j]) * AUST[36 + j];
      float p = 1.0f / (1.0f + expf(-xh));
      float h = p * x + (1.0f - p) * auA1[j] * x;
      w += h * auW2[j];
    }
    sW[t] = w;
  }
  __syncthreads();
  {
    int k = tid & 63, g = tid >> 6;
    float c = 0.f;
    for (int r = g * 50; r < g * 50 + 50; ++r) c += sW[r] * sHe[r * 65 + k];
    sPart[tid] = c;
  }
  __syncthreads();
  if (tid < 64) {
    float cur = sPart[tid] + sPart[64 + tid] + sPart[128 + tid] + sPart[192 + tid];
    sX[tid] = Utab[(size_t)user[b] * 64 + tid];
    sX[64 + tid] = sIe[tid];
    sX[128 + tid] = Ctab[(size_t)cate[b] * 64 + tid];
    sX[192 + tid] = cur;
  }
  __syncthreads();
  if (tid < 80) {
    float a = b1[tid];
    for (int k = 0; k < 256; ++k) a += sX[k] * W1[k * 80 + tid];
    Y1[b * 80 + tid] = a;
  }
}

// ---------------- per-channel batch stats over [B, nch] ----------------
__global__ __launch_bounds__(256) void k_colstats(const float* __restrict__ src,
                                                  int nch, float* __restrict__ st) {
  int ch = blockIdx.x, tid = threadIdx.x;
  float s1 = 0.f, s2 = 0.f;
  for (int r = tid; r < BB; r += 256) {
    float v = src[r * nch + ch];
    s1 += v;
    s2 += v * v;
  }
  __shared__ float r1[256], r2[256];
  r1[tid] = s1;
  r2[tid] = s2;
  __syncthreads();
  for (int off = 128; off > 0; off >>= 1) {
    if (tid < off) { r1[tid] += r1[tid + off]; r2[tid] += r2[tid + off]; }
    __syncthreads();
  }
  if (tid == 0) {
    float m = r1[0] / (float)BB;
    float var = r2[0] / (float)BB - m * m;
    st[ch] = m;
    st[nch + ch] = 1.0f / sqrtf(var + 1e-8f);
  }
}

// ---------------- MLP layer 2: y2pre = dice(y1) @ W2 + b2 ----------------
__global__ __launch_bounds__(128) void k_mlp2(const float* __restrict__ Y1,
                                              const float* __restrict__ ST80,
                                              const float* __restrict__ a1,
                                              const float* __restrict__ W2,
                                              const float* __restrict__ b2,
                                              float* __restrict__ Y2) {
  int b = blockIdx.x, tid = threadIdx.x;
  __shared__ float sY[80];
  if (tid < 80) {
    float x = Y1[b * 80 + tid];
    float xh = (x - ST80[tid]) * ST80[80 + tid];
    float p = 1.0f / (1.0f + expf(-xh));
    sY[tid] = p * x + (1.0f - p) * a1[tid] * x;
  }
  __syncthreads();
  if (tid < 40) {
    float a = b2[tid];
    for (int k = 0; k < 80; ++k) a += sY[k] * W2[k * 40 + tid];
    Y2[b * 40 + tid] = a;
  }
}

// ---------------- MLP layer 3: out = dice(y2) @ W3 + b3 ----------------
__global__ __launch_bounds__(64) void k_mlp3(const float* __restrict__ Y2,
                                             const float* __restrict__ ST40,
                                             const float* __restrict__ a2,
                                             const float* __restrict__ W3,
                                             const float* __restrict__ b3,
                                             float* __restrict__ out) {
  int b = blockIdx.x, tid = threadIdx.x;
  __shared__ float sY[40];
  if (tid < 40) {
    float x = Y2[b * 40 + tid];
    float xh = (x - ST40[tid]) * ST40[40 + tid];
    float p = 1.0f / (1.0f + expf(-xh));
    sY[tid] = p * x + (1.0f - p) * a2[tid] * x;
  }
  __syncthreads();
  if (tid < 2) {
    float a = b3[tid];
    for (int k = 0; k < 40; ++k) a += sY[k] * W3[k * 2 + tid];
    out[b * 2 + tid] = a;
  }
}

extern "C" void kernel_launch(void* const* d_in, const int* in_sizes, int n_in,
                              void* d_out, int out_size, void* d_ws, size_t ws_size,
                              hipStream_t stream) {
  const int* user = (const int*)d_in[0];
  const int* hist = (const int*)d_in[1];
  const int* item = (const int*)d_in[2];
  const int* cate = (const int*)d_in[3];
  const float* Utab = (const float*)d_in[4];
  const float* Itab = (const float*)d_in[5];
  const float* Ctab = (const float*)d_in[6];
  const float* auW1 = (const float*)d_in[7];
  const float* auB1 = (const float*)d_in[8];
  const float* auA1 = (const float*)d_in[9];
  const float* auW2 = (const float*)d_in[10];
  const float* auB2 = (const float*)d_in[11];
  const float* W1 = (const float*)d_in[12];
  const float* b1 = (const float*)d_in[13];
  const float* a1 = (const float*)d_in[14];
  const float* W2 = (const float*)d_in[15];
  const float* b2 = (const float*)d_in[16];
  const float* a2 = (const float*)d_in[17];
  const float* W3 = (const float*)d_in[18];
  const float* b3 = (const float*)d_in[19];
  float* out = (float*)d_out;

  float* ws = (float*)d_ws;
  float* WE = ws;                       // 2304
  float* TBuf = WE + 2304;              // B*36
  float* PART = TBuf + BB * 36;         // B*72
  float* AUST = PART + BB * 72;         // 72
  float* Y1 = AUST + 72;                // B*80
  float* ST80 = Y1 + BB * 80;           // 160
  float* Y2 = ST80 + 160;               // B*40
  float* ST40 = Y2 + BB * 40;           // 80

  k_prep_we<<<9, 256, 0, stream>>>(auW1, WE);
  k_prep_tb<<<BB, 64, 0, stream>>>(item, Itab, auW1, auB1, TBuf);
  k_au1<<<BB, 256, 0, stream>>>(hist, item, Itab, WE, TBuf, auW1, PART);
  k_aust<<<36, 256, 0, stream>>>(PART, AUST);
  k_au2<<<BB, 256, 0, stream>>>(hist, item, user, cate, Itab, Utab, Ctab, WE,
                                TBuf, auW1, AUST, auA1, auW2, auB2, W1, b1, Y1);
  k_colstats<<<80, 256, 0, stream>>>(Y1, 80, ST80);
  k_mlp2<<<BB, 128, 0, stream>>>(Y1, ST80, a1, W2, b2, Y2);
  k_colstats<<<40, 256, 0, stream>>>(Y2, 40, ST40);
  k_mlp3<<<BB, 64, 0, stream>>>(Y2, ST40, a2, W3, b3, out);
}

// Round 2
// 276.076 us; speedup vs baseline: 1.7107x; 1.7107x over previous
//
#include <hip/hip_runtime.h>
#include <math.h>

#define BB 4096
#define TT 200
#define NT (BB*TT)
#define CORE_BLOCKS (NT/256)   // 3200

// ---------------- prep: WE = Wa + Wc ----------------
__global__ __launch_bounds__(256) void k_prep_we(const float* __restrict__ auW1,
                                                 float* __restrict__ WE) {
  int i = blockIdx.x * 256 + threadIdx.x;
  if (i < 64 * 36) WE[i] = auW1[i] + auW1[128 * 36 + i];
}

// ---------------- prep: tb[b][36] = ie_b @ (Wb - Wc) + au_b1 ----------------
__global__ __launch_bounds__(64) void k_prep_tb(const int* __restrict__ item,
                                                const float* __restrict__ Itab,
                                                const float* __restrict__ auW1,
                                                const float* __restrict__ auB1,
                                                float* __restrict__ TBuf) {
  int b = blockIdx.x, tid = threadIdx.x;
  __shared__ float sIe[64];
  sIe[tid] = Itab[(size_t)item[b] * 64 + tid];
  __syncthreads();
  if (tid < 36) {
    float a = auB1[tid];
    for (int k = 0; k < 64; ++k)
      a += sIe[k] * (auW1[(64 + k) * 36 + tid] - auW1[(128 + k) * 36 + tid]);
    TBuf[b * 36 + tid] = a;
  }
}

// ---------------- core matvec: acc = tb + he @ (WE + ie*WD) ----------------
// PASS 1: emit per-block stats partials.  PASS 2: dice + attention weight.
template<int PASS>
__global__ __launch_bounds__(256) void k_core(
    const int* __restrict__ hist, const int* __restrict__ item,
    const float* __restrict__ Itab, const float* __restrict__ WE,
    const float* __restrict__ WD, const float* __restrict__ TBuf,
    const float* __restrict__ AUST, const float* __restrict__ auA1,
    const float* __restrict__ auW2, const float* __restrict__ auB2,
    float* __restrict__ PART, float* __restrict__ Wbuf) {
  extern __shared__ float smem[];
  const int tid = threadIdx.x;
  const int s = blockIdx.x * 256;
  const int bLo = s / TT;
  const int bHi = (s + 255) / TT;
  const int nb = bHi - bLo + 1;            // <= 3 (2 boundaries max in a 256 window)
  float* sWB = smem;                        // [nb][64][36]
  float* sIe = smem + 3 * 2304;             // [nb][64]
  float* sTB = sIe + 3 * 64;                // [nb][36]
  for (int i = tid; i < nb * 64; i += 256)
    sIe[i] = Itab[(size_t)item[bLo + (i >> 6)] * 64 + (i & 63)];
  for (int i = tid; i < nb * 36; i += 256) {
    int li = i / 36;
    sTB[i] = TBuf[(bLo + li) * 36 + (i - li * 36)];
  }
  __syncthreads();
  for (int i = tid; i < nb * 2304; i += 256) {
    int li = i / 2304, r = i - li * 2304, k = r / 36;
    sWB[i] = WE[r] + sIe[(li << 6) + k] * WD[r];
  }
  __syncthreads();

  const int task = s + tid;
  const int b = task / TT;
  const int li = b - bLo;
  const int row = hist[task];
  const float4* __restrict__ rp4 = (const float4*)(Itab + (size_t)row * 64);
  const float* wb = sWB + li * 2304;

  float acc[36];
  {
    const float* tb = sTB + li * 36;
#pragma unroll
    for (int j = 0; j < 36; ++j) acc[j] = tb[j];
  }

  float4 qA[4], qB[4];
#pragma unroll
  for (int q = 0; q < 4; ++q) qA[q] = rp4[q];
#pragma unroll
  for (int kc = 0; kc < 4; ++kc) {
    const float* curq = (kc & 1) ? (const float*)qB : (const float*)qA;
    float4* nxtq = (kc & 1) ? qA : qB;
    if (kc < 3) {
#pragma unroll
      for (int q = 0; q < 4; ++q) nxtq[q] = rp4[(kc + 1) * 4 + q];
    }
#pragma unroll
    for (int kk = 0; kk < 16; ++kk) {
      float hk = curq[kk];
      const float4* w4 = (const float4*)(wb + (kc * 16 + kk) * 36);
#pragma unroll
      for (int jg = 0; jg < 9; ++jg) {
        float4 wv = w4[jg];
        acc[jg * 4 + 0] += hk * wv.x;
        acc[jg * 4 + 1] += hk * wv.y;
        acc[jg * 4 + 2] += hk * wv.z;
        acc[jg * 4 + 3] += hk * wv.w;
      }
    }
  }

  if (PASS == 1) {
    __syncthreads();                 // everyone done reading sWB; alias as reduction buf
    float* red = smem;               // [256][37]
    float* red2 = smem + 256 * 37;   // [252][2]
#pragma unroll
    for (int j = 0; j < 36; ++j) red[tid * 37 + j] = acc[j];
    __syncthreads();
    if (tid < 252) {
      int ch = tid / 7, seg = tid - ch * 7;
      int r0 = seg * 37, r1 = r0 + 37 < 256 ? r0 + 37 : 256;
      float s1 = 0.f, s2 = 0.f;
      for (int r = r0; r < r1; ++r) {
        float v = red[r * 37 + ch];
        s1 += v;
        s2 += v * v;
      }
      red2[tid * 2] = s1;
      red2[tid * 2 + 1] = s2;
    }
    __syncthreads();
    if (tid < 36) {
      float s1 = 0.f, s2 = 0.f;
      for (int seg = 0; seg < 7; ++seg) {
        s1 += red2[(tid * 7 + seg) * 2];
        s2 += red2[(tid * 7 + seg) * 2 + 1];
      }
      PART[blockIdx.x * 72 + tid] = s1;
      PART[blockIdx.x * 72 + 36 + tid] = s2;
    }
  } else {
    float w = auB2[0];
#pragma unroll
    for (int j = 0; j < 36; ++j) {
      float x = acc[j];
      float xh = (x - AUST[j]) * AUST[36 + j];
      float p = 1.0f / (1.0f + __expf(-xh));
      float a = auA1[j];
      w += x * (a + p * (1.0f - a)) * auW2[j];
    }
    Wbuf[task] = w;
  }
}

// ---------------- AU stats finalize ----------------
__global__ __launch_bounds__(256) void k_aust(const float* __restrict__ PART,
                                              float* __restrict__ AUST) {
  int ch = blockIdx.x, tid = threadIdx.x;   // grid 36
  float s1 = 0.f, s2 = 0.f;
  for (int blk = tid; blk < CORE_BLOCKS; blk += 256) {
    s1 += PART[blk * 72 + ch];
    s2 += PART[blk * 72 + 36 + ch];
  }
  __shared__ float r1[256], r2[256];
  r1[tid] = s1;
  r2[tid] = s2;
  __syncthreads();
  for (int off = 128; off > 0; off >>= 1) {
    if (tid < off) { r1[tid] += r1[tid + off]; r2[tid] += r2[tid + off]; }
    __syncthreads();
  }
  if (tid == 0) {
    float m = r1[0] / (float)NT;
    float var = r2[0] / (float)NT - m * m;
    AUST[ch] = m;
    AUST[36 + ch] = 1.0f / sqrtf(var + 1e-8f);
  }
}

// ---------------- pooling + x-concat + MLP layer1 ----------------
__global__ __launch_bounds__(256) void k_pool(
    const int* __restrict__ hist, const int* __restrict__ user,
    const int* __restrict__ item, const int* __restrict__ cate,
    const float* __restrict__ Itab, const float* __restrict__ Utab,
    const float* __restrict__ Ctab, const float* __restrict__ Wbuf,
    const float* __restrict__ W1, const float* __restrict__ b1,
    float* __restrict__ Y1) {
  int b = blockIdx.x, tid = threadIdx.x;
  __shared__ float sW[TT];
  __shared__ int sRows[TT];
  __shared__ float sPart[256];
  __shared__ float sX[256];
  if (tid < TT) {
    sW[tid] = Wbuf[b * TT + tid];
    sRows[tid] = hist[b * TT + tid];
  }
  __syncthreads();
  {
    int k = tid & 63, g = tid >> 6;
    float c = 0.f;
    int t0 = g * 50;
#pragma unroll 5
    for (int t = t0; t < t0 + 50; ++t)
      c += sW[t] * Itab[(size_t)sRows[t] * 64 + k];
    sPart[tid] = c;
  }
  __syncthreads();
  if (tid < 64) {
    float cur = sPart[tid] + sPart[64 + tid] + sPart[128 + tid] + sPart[192 + tid];
    sX[tid] = Utab[(size_t)user[b] * 64 + tid];
    sX[64 + tid] = Itab[(size_t)item[b] * 64 + tid];
    sX[128 + tid] = Ctab[(size_t)cate[b] * 64 + tid];
    sX[192 + tid] = cur;
  }
  __syncthreads();
  if (tid < 80) {
    float a = b1[tid];
    for (int k = 0; k < 256; ++k) a += sX[k] * W1[k * 80 + tid];
    Y1[b * 80 + tid] = a;
  }
}

// ---------------- per-channel batch stats over [B, nch] ----------------
__global__ __launch_bounds__(256) void k_colstats(const float* __restrict__ src,
                                                  int nch, float* __restrict__ st) {
  int ch = blockIdx.x, tid = threadIdx.x;
  float s1 = 0.f, s2 = 0.f;
  for (int r = tid; r < BB; r += 256) {
    float v = src[r * nch + ch];
    s1 += v;
    s2 += v * v;
  }
  __shared__ float r1[256], r2[256];
  r1[tid] = s1;
  r2[tid] = s2;
  __syncthreads();
  for (int off = 128; off > 0; off >>= 1) {
    if (tid < off) { r1[tid] += r1[tid + off]; r2[tid] += r2[tid + off]; }
    __syncthreads();
  }
  if (tid == 0) {
    float m = r1[0] / (float)BB;
    float var = r2[0] / (float)BB - m * m;
    st[ch] = m;
    st[nch + ch] = 1.0f / sqrtf(var + 1e-8f);
  }
}

// ---------------- MLP layer 2 ----------------
__global__ __launch_bounds__(128) void k_mlp2(const float* __restrict__ Y1,
                                              const float* __restrict__ ST80,
                                              const float* __restrict__ a1,
                                              const float* __restrict__ W2,
                                              const float* __restrict__ b2,
                                              float* __restrict__ Y2) {
  int b = blockIdx.x, tid = threadIdx.x;
  __shared__ float sY[80];
  if (tid < 80) {
    float x = Y1[b * 80 + tid];
    float xh = (x - ST80[tid]) * ST80[80 + tid];
    float p = 1.0f / (1.0f + expf(-xh));
    sY[tid] = p * x + (1.0f - p) * a1[tid] * x;
  }
  __syncthreads();
  if (tid < 40) {
    float a = b2[tid];
    for (int k = 0; k < 80; ++k) a += sY[k] * W2[k * 40 + tid];
    Y2[b * 40 + tid] = a;
  }
}

// ---------------- MLP layer 3 ----------------
__global__ __launch_bounds__(64) void k_mlp3(const float* __restrict__ Y2,
                                             const float* __restrict__ ST40,
                                             const float* __restrict__ a2,
                                             const float* __restrict__ W3,
                                             const float* __restrict__ b3,
                                             float* __restrict__ out) {
  int b = blockIdx.x, tid = threadIdx.x;
  __shared__ float sY[40];
  if (tid < 40) {
    float x = Y2[b * 40 + tid];
    float xh = (x - ST40[tid]) * ST40[40 + tid];
    float p = 1.0f / (1.0f + expf(-xh));
    sY[tid] = p * x + (1.0f - p) * a2[tid] * x;
  }
  __syncthreads();
  if (tid < 2) {
    float a = b3[tid];
    for (int k = 0; k < 40; ++k) a += sY[k] * W3[k * 2 + tid];
    out[b * 2 + tid] = a;
  }
}

extern "C" void kernel_launch(void* const* d_in, const int* in_sizes, int n_in,
                              void* d_out, int out_size, void* d_ws, size_t ws_size,
                              hipStream_t stream) {
  const int* user = (const int*)d_in[0];
  const int* hist = (const int*)d_in[1];
  const int* item = (const int*)d_in[2];
  const int* cate = (const int*)d_in[3];
  const float* Utab = (const float*)d_in[4];
  const float* Itab = (const float*)d_in[5];
  const float* Ctab = (const float*)d_in[6];
  const float* auW1 = (const float*)d_in[7];
  const float* auB1 = (const float*)d_in[8];
  const float* auA1 = (const float*)d_in[9];
  const float* auW2 = (const float*)d_in[10];
  const float* auB2 = (const float*)d_in[11];
  const float* W1 = (const float*)d_in[12];
  const float* b1 = (const float*)d_in[13];
  const float* a1 = (const float*)d_in[14];
  const float* W2 = (const float*)d_in[15];
  const float* b2 = (const float*)d_in[16];
  const float* a2 = (const float*)d_in[17];
  const float* W3 = (const float*)d_in[18];
  const float* b3 = (const float*)d_in[19];
  float* out = (float*)d_out;

  float* ws = (float*)d_ws;
  float* WE = ws;                        // 2304
  float* TBuf = WE + 2304;               // B*36
  float* PART = TBuf + BB * 36;          // 3200*72
  float* AUST = PART + CORE_BLOCKS * 72; // 72
  float* Wbuf = AUST + 72;               // NT
  float* Y1 = Wbuf + NT;                 // B*80
  float* ST80 = Y1 + BB * 80;            // 160
  float* Y2 = ST80 + 160;                // B*40
  float* ST40 = Y2 + BB * 40;            // 80

  const float* WD = auW1 + 192 * 36;

  k_prep_we<<<9, 256, 0, stream>>>(auW1, WE);
  k_prep_tb<<<BB, 64, 0, stream>>>(item, Itab, auW1, auB1, TBuf);
  k_core<1><<<CORE_BLOCKS, 256, (256 * 37 + 252 * 2) * 4, stream>>>(
      hist, item, Itab, WE, WD, TBuf, nullptr, nullptr, nullptr, nullptr,
      PART, nullptr);
  k_aust<<<36, 256, 0, stream>>>(PART, AUST);
  k_core<2><<<CORE_BLOCKS, 256, (3 * 2304 + 3 * 64 + 3 * 36) * 4, stream>>>(
      hist, item, Itab, WE, WD, TBuf, AUST, auA1, auW2, auB2,
      nullptr, Wbuf);
  k_pool<<<BB, 256, 0, stream>>>(hist, user, item, cate, Itab, Utab, Ctab,
                                 Wbuf, W1, b1, Y1);
  k_colstats<<<80, 256, 0, stream>>>(Y1, 80, ST80);
  k_mlp2<<<BB, 128, 0, stream>>>(Y1, ST80, a1, W2, b2, Y2);
  k_colstats<<<40, 256, 0, stream>>>(Y2, 40, ST40);
  k_mlp3<<<BB, 64, 0, stream>>>(Y2, ST40, a2, W3, b3, out);
}